// Round 1
// baseline (138.829 us; speedup 1.0000x reference)
//
#include <hip/hip_runtime.h>
#include <math.h>

// Problem constants (fixed by the reference).
constexpr int kN  = 250000;
constexpr int kC  = 32;
constexpr int kFC = 16;
constexpr int kFN = 16;
constexpr int kV  = 64;
constexpr int kBlock = 1024;

// ---------------------------------------------------------------------------
// LDS-gather log-space fast path + CANDIDATE-ONLY exact fallback.
//
// Fast path (per sample, per class):
//   T_c = K_c + sum_f Lcat[c][f][idx_f] + sum_f (A_cf * x_f^2 + B_cf * x_f)
// where Lcat = logf(cat_probs) staged in LDS (131072 B, <=2-way bank
// conflicts since each row is 64 floats = 2x bank count), A = -0.5/s^2,
// B = m/s^2, and C = -0.5 m^2/s^2 + log(1/(2*pi*s^2)) folded into K_c.
// (A,B,K) live in ws -> uniform addresses -> scalar K$ loads.
//
// Error bound: gaussian quadratic form ~<=1.2e-3 (|a|<=~few hundred, fma
// roundings), cat log-sum ~<=1.5e-4 (16x 1-ulp logf at |L|<=3 + sum
// roundings at |sum|<=48), K rounding ~1e-5  =>  total B ~<= 2e-3.
// Accept fast result iff T_best >= -86 AND top-2 gap >= 8e-3 (= 4x bound).
// Otherwise fallback, exact-scoring ONLY candidates with
// T_c >= T_best - 1.6e-2 (excluded classes provably lose: their true
// log-score <= T_c + 2e-3 <= best - 1.4e-2 < best - 2e-3 <= true best).
// If T_best < -86 (deep underflow) evaluate ALL classes with the
// round-1-validated exact sequence (denormals / all-zero ties -> first
// max = ref semantics).
// ---------------------------------------------------------------------------

// d_ws layout (floats): [0..31] K_c ; [32..1055] interleaved {A,B} per (c,f)
// -> 4224 bytes, identical footprint to the previous (verified) version.
__global__ __launch_bounds__(256) void nbc_prep(
    const float* __restrict__ class_probs,
    const float* __restrict__ means,
    const float* __restrict__ stds,
    float* __restrict__ ws)
{
    const int t = threadIdx.x;
    const float two_pi = 2.0f * (float)M_PI;
    for (int i = t; i < kC * kFN; i += 256) {
        float m  = means[i];
        float s  = stds[i];
        float rs = 1.0f / s;
        ws[32 + 2 * i]     = -0.5f * rs * rs;   // A
        ws[32 + 2 * i + 1] = m * rs * rs;       // B
    }
    if (t < kC) {
        float k = logf(class_probs[t]);
        for (int f = 0; f < kFN; ++f) {
            float s  = stds[t * kFN + f];
            float m  = means[t * kFN + f];
            float rs = 1.0f / s;
            k += logf(1.0f / (two_pi * (s * s)));
            k += -0.5f * (m * rs) * (m * rs);   // C term of the quadratic
        }
        ws[t] = k;
    }
}

__global__ __launch_bounds__(kBlock, 4) void nbc_main(
    const int*   __restrict__ X_cat,
    const float* __restrict__ X_num,
    const float* __restrict__ class_probs,
    const float* __restrict__ cat_probs,
    const float* __restrict__ means,
    const float* __restrict__ stds,
    const float* __restrict__ ws,
    int* __restrict__ out)
{
    // Full log-probability table in LDS: [c][f][v], 32*16*64 floats = 128 KiB.
    __shared__ float lcat[kC * kFC * kV];

    const int tid = threadIdx.x;

    // ---- stage: vectorized log-copy of cat_probs into LDS ----
    {
        const float4* __restrict__ src = reinterpret_cast<const float4*>(cat_probs);
        float4* dst = reinterpret_cast<float4*>(lcat);
        #pragma unroll
        for (int i = 0; i < (kC * kFC * kV / 4) / kBlock; ++i) {  // 8 iters
            int j = i * kBlock + tid;
            float4 v = src[j];
            dst[j] = make_float4(logf(v.x), logf(v.y), logf(v.z), logf(v.w));
        }
    }
    __syncthreads();

    const int n = blockIdx.x * kBlock + tid;
    if (n >= kN) return;

    // Vector-load the 16 categorical indices and 16 numeric features.
    int   idx[kFC];
    float x  [kFN];
    float xx [kFN];
    {
        const int4* p4 = reinterpret_cast<const int4*>(X_cat + (size_t)n * kFC);
        int4 a0 = p4[0], a1 = p4[1], a2 = p4[2], a3 = p4[3];
        idx[0]=a0.x;  idx[1]=a0.y;  idx[2]=a0.z;  idx[3]=a0.w;
        idx[4]=a1.x;  idx[5]=a1.y;  idx[6]=a1.z;  idx[7]=a1.w;
        idx[8]=a2.x;  idx[9]=a2.y;  idx[10]=a2.z; idx[11]=a2.w;
        idx[12]=a3.x; idx[13]=a3.y; idx[14]=a3.z; idx[15]=a3.w;

        const float4* q4 = reinterpret_cast<const float4*>(X_num + (size_t)n * kFN);
        float4 b0 = q4[0], b1 = q4[1], b2 = q4[2], b3 = q4[3];
        x[0]=b0.x;  x[1]=b0.y;  x[2]=b0.z;  x[3]=b0.w;
        x[4]=b1.x;  x[5]=b1.y;  x[6]=b1.z;  x[7]=b1.w;
        x[8]=b2.x;  x[9]=b2.y;  x[10]=b2.z; x[11]=b2.w;
        x[12]=b3.x; x[13]=b3.y; x[14]=b3.z; x[15]=b3.w;
        #pragma unroll
        for (int f = 0; f < kFN; ++f) xx[f] = x[f] * x[f];
    }

    const float*  __restrict__ K = ws;                                 // scalar K$
    const float2* __restrict__ W = reinterpret_cast<const float2*>(ws + 32); // {A,B}

    // ---- fast path: log-space argmax with top-2 tracking ----
    float best = -INFINITY, second = -INFINITY;
    int   besti = 0;

    #pragma unroll 2
    for (int c = 0; c < kC; ++c) {
        const float* __restrict__ L = lcat + (c << 10);  // c*kFC*kV
        float lc = L[idx[0]];
        #pragma unroll
        for (int f = 1; f < kFC; ++f) {
            lc += L[(f << 6) + idx[f]];
        }

        float ga = 0.0f, gb = 0.0f;
        #pragma unroll
        for (int f = 0; f < kFN; ++f) {
            float2 q = W[(c << 4) + f];       // uniform -> scalar loads
            ga = fmaf(xx[f], q.x, ga);
            gb = fmaf(x[f],  q.y, gb);
        }

        float T = (K[c] + lc) + (ga + gb);
        if (T > best)        { second = best; best = T; besti = c; }
        else if (T > second) { second = T; }
    }

    if (best >= -86.0f && (best - second) >= 8.0e-3f) {
        out[n] = besti;
        return;
    }

    // ---- fallback: exact scoring of candidate classes only ----
    // thr = -inf in the deep-underflow case -> all classes exact (ref semantics).
    const float thr    = (best >= -86.0f) ? (best - 1.6e-2f) : -INFINITY;
    const float two_pi = 2.0f * (float)M_PI;
    float bb = -INFINITY;
    int   bi = 0;

    for (int c = 0; c < kC; ++c) {
        // Recompute T_c (same data as fast loop; only the <=2e-3 bound matters).
        const float* __restrict__ L = lcat + (c << 10);
        float lc = L[idx[0]];
        #pragma unroll
        for (int f = 1; f < kFC; ++f) lc += L[(f << 6) + idx[f]];
        float ga = 0.0f, gb = 0.0f;
        #pragma unroll
        for (int f = 0; f < kFN; ++f) {
            float2 q = W[(c << 4) + f];
            ga = fmaf(xx[f], q.x, ga);
            gb = fmaf(x[f],  q.y, gb);
        }
        float T = (K[c] + lc) + (ga + gb);

        if (T >= thr) {
            // Exact reference numerics (round-1 validated, bit-identical).
            const float* __restrict__ row = cat_probs + (size_t)c * (kFC * kV);
            float cat = row[idx[0]];
            #pragma unroll
            for (int f = 1; f < kFC; ++f) {
                cat *= row[(f << 6) + idx[f]];
            }
            float num;
            #pragma unroll
            for (int f = 0; f < kFN; ++f) {
                float m = means[c * kFN + f];
                float s = stds [c * kFN + f];
                float inv = 1.0f / (two_pi * (s * s));
                float z = (x[f] - m) / s;              // IEEE divide
                float e = expf(-0.5f * (z * z));
                float lik = inv * e;
                num = (f == 0) ? lik : num * lik;
            }
            float pred = (class_probs[c] * cat) * num; // ((cp*cat)*num) like ref
            if (pred > bb) { bb = pred; bi = c; }      // strict > -> first max
        }
    }
    out[n] = bi;
}

extern "C" void kernel_launch(void* const* d_in, const int* in_sizes, int n_in,
                              void* d_out, int out_size, void* d_ws, size_t ws_size,
                              hipStream_t stream) {
    const int*   X_cat       = (const int*)  d_in[0];
    const float* X_num       = (const float*)d_in[1];
    const float* class_probs = (const float*)d_in[2];
    const float* cat_probs   = (const float*)d_in[3];
    const float* means       = (const float*)d_in[4];
    const float* stds        = (const float*)d_in[5];
    int*   out = (int*)d_out;
    float* ws  = (float*)d_ws;   // 4224 bytes used

    hipLaunchKernelGGL(nbc_prep, dim3(1), dim3(256), 0, stream,
                       class_probs, means, stds, ws);

    dim3 block(kBlock);
    dim3 grid((kN + kBlock - 1) / kBlock);
    hipLaunchKernelGGL(nbc_main, grid, block, 0, stream,
                       X_cat, X_num, class_probs, cat_probs, means, stds, ws, out);
}